// Round 12
// baseline (141.876 us; speedup 1.0000x reference)
//
#include <hip/hip_runtime.h>
#include <math.h>

#define BB_   2
#define CIN_  256
#define NTOK_ 2048
#define FF_   512
#define COUT_ 256
#define NH_   8
#define DH_   64
#define HW_   128
#define BNEPS_ 1e-5f
#define SCALE_LOG2_ 0.09016844005556021f  /* log2(e)/16, folded into K at qkv */

typedef __attribute__((ext_vector_type(8))) short short8;
typedef __attribute__((ext_vector_type(4))) short bfx4;
typedef __attribute__((ext_vector_type(4))) float f32x4;

#if __has_builtin(__builtin_amdgcn_mfma_f32_16x16x16_bf16)
#define MFMA16(a, b, c) __builtin_amdgcn_mfma_f32_16x16x16_bf16(a, b, c, 0, 0, 0)
#else
#define MFMA16(a, b, c) __builtin_amdgcn_mfma_f32_16x16x16bf16_1k(a, b, c, 0, 0, 0)
#endif
#define MFMA32(a, b, c) __builtin_amdgcn_mfma_f32_16x16x32_bf16(a, b, c, 0, 0, 0)

__device__ inline unsigned short f2bf(float f) {
  union { float f; unsigned u; } v; v.f = f;
  unsigned r = (v.u + 0x7FFF + ((v.u >> 16) & 1)) >> 16;  // RNE
  return (unsigned short)r;
}

// async global->LDS DMA, 16 B per lane; LDS dest = wave-uniform base + lane*16
__device__ __forceinline__ void dma16(const unsigned short* g, unsigned short* l) {
  __builtin_amdgcn_global_load_lds(
      (const __attribute__((address_space(1))) void*)g,
      (__attribute__((address_space(3))) void*)l, 16, 0, 0);
}

// ---------------------------------------------------------------------------
// Kernel 0: prep — x fp32 [b][c][n] -> xT bf16 [b][n][c]; weights -> bf16.
// ---------------------------------------------------------------------------
__global__ __launch_bounds__(256) void prep_kernel(
    const float* __restrict__ x, const float* __restrict__ WK,
    const float* __restrict__ WQ, const float* __restrict__ WV,
    const float* __restrict__ Wo, unsigned short* __restrict__ xT,
    unsigned short* __restrict__ Wkb, unsigned short* __restrict__ Wqb,
    unsigned short* __restrict__ Wvb, unsigned short* __restrict__ Wob) {
  __shared__ float T[64 * 65];
  const int tid = threadIdx.x;
  const int bid = blockIdx.x;
  if (bid < 256) {
    const int b = bid >> 7;
    const int rem = bid & 127;
    const int n0 = (rem >> 2) * 64;
    const int c0 = (rem & 3) * 64;
#pragma unroll
    for (int p = 0; p < 4; ++p) {
      const int idx = tid + 256 * p;
      const int row = idx >> 4, col = (idx & 15) * 4;
      const float4 v =
          *(const float4*)(x + (size_t)(b * CIN_ + c0 + row) * NTOK_ + n0 + col);
      T[row * 65 + col + 0] = v.x; T[row * 65 + col + 1] = v.y;
      T[row * 65 + col + 2] = v.z; T[row * 65 + col + 3] = v.w;
    }
    __syncthreads();
#pragma unroll
    for (int p = 0; p < 2; ++p) {
      const int idx = tid + 256 * p;
      const int nl = idx >> 3, c8 = (idx & 7) * 8;
      unsigned short u[8];
#pragma unroll
      for (int i = 0; i < 8; ++i) u[i] = f2bf(T[(c8 + i) * 65 + nl]);
      *(uint4*)(xT + ((size_t)(b * NTOK_ + n0 + nl)) * CIN_ + c0 + c8) =
          *(uint4*)u;
    }
  } else {
    const int t = bid - 256;
    const int which = t >> 5, blk = t & 31;
    const float* src = which == 0 ? WK : which == 1 ? WQ : which == 2 ? WV : Wo;
    unsigned short* dst = which == 0 ? Wkb : which == 1 ? Wqb : which == 2 ? Wvb : Wob;
    const int base = blk * 4096 + tid * 16;
#pragma unroll
    for (int p = 0; p < 4; ++p) {
      const float4 v = *(const float4*)(src + base + p * 4);
      ushort4 u;
      u.x = f2bf(v.x); u.y = f2bf(v.y); u.z = f2bf(v.z); u.w = f2bf(v.w);
      *(ushort4*)(dst + base + p * 4) = u;
    }
  }
}

// ---------------------------------------------------------------------------
// Kernel 1: QKV projection via MFMA. 128f x 64n tile, 768 blocks, 3 blocks/CU.
// K pre-scaled by log2(e)/16. K,Q -> [b][h][n][d]; V (swapped) -> [b][h][d][n].
// ---------------------------------------------------------------------------
__global__ __launch_bounds__(256, 3) void qkv_kernel(
    const unsigned short* __restrict__ xT, const unsigned short* __restrict__ Wkb,
    const unsigned short* __restrict__ Wqb, const unsigned short* __restrict__ Wvb,
    unsigned short* __restrict__ Kb, unsigned short* __restrict__ Qb,
    unsigned short* __restrict__ Vt) {
  __shared__ unsigned short Wsh[128 * 72];
  __shared__ unsigned short Xsh[64 * 72];
  const int tid = threadIdx.x;
  const int lane = tid & 63, w = tid >> 6;
  const int lx = lane & 15, q = lane >> 4;
  const int wm = w >> 1, wn = w & 1;
  const int n0 = blockIdx.x * 64;
  const int f0 = blockIdx.y * 128;
  const int b = blockIdx.z / 3, which = blockIdx.z % 3;
  const unsigned short* Wb = which == 0 ? Wkb : which == 1 ? Wqb : Wvb;

  const int srow = tid >> 3;
  const int soff = (tid & 7) * 8;
  const unsigned short* Wg = Wb + (size_t)(f0 + srow) * CIN_ + soff;
  const unsigned short* Xg = xT + ((size_t)(b * NTOK_ + n0 + srow)) * CIN_ + soff;

  uint4 wr[4], xr[2];
#pragma unroll
  for (int r = 0; r < 4; ++r) wr[r] = *(const uint4*)(Wg + (size_t)(32 * r) * CIN_);
#pragma unroll
  for (int r = 0; r < 2; ++r) xr[r] = *(const uint4*)(Xg + (size_t)(32 * r) * CIN_);

  f32x4 acc[4][2];
#pragma unroll
  for (int i = 0; i < 4; ++i)
#pragma unroll
    for (int j = 0; j < 2; ++j) acc[i][j] = (f32x4){0.f, 0.f, 0.f, 0.f};

  for (int kk = 0; kk < 4; ++kk) {
    __syncthreads();
#pragma unroll
    for (int r = 0; r < 4; ++r) *(uint4*)(Wsh + (srow + 32 * r) * 72 + soff) = wr[r];
#pragma unroll
    for (int r = 0; r < 2; ++r) *(uint4*)(Xsh + (srow + 32 * r) * 72 + soff) = xr[r];
    if (kk < 3) {
      const int c0 = (kk + 1) * 64;
#pragma unroll
      for (int r = 0; r < 4; ++r) wr[r] = *(const uint4*)(Wg + (size_t)(32 * r) * CIN_ + c0);
#pragma unroll
      for (int r = 0; r < 2; ++r) xr[r] = *(const uint4*)(Xg + (size_t)(32 * r) * CIN_ + c0);
    }
    __syncthreads();
    short8 xF[2][2];
#pragma unroll
    for (int i = 0; i < 2; ++i) {
      xF[i][0] = *(const short8*)(Xsh + (32 * wn + 16 * i + lx) * 72 + q * 8);
      xF[i][1] = *(const short8*)(Xsh + (32 * wn + 16 * i + lx) * 72 + 32 + q * 8);
    }
    if (which < 2) {
#pragma unroll
      for (int i = 0; i < 4; ++i) {
        const short8 w0 = *(const short8*)(Wsh + (64 * wm + 16 * i + lx) * 72 + q * 8);
        const short8 w1 = *(const short8*)(Wsh + (64 * wm + 16 * i + lx) * 72 + 32 + q * 8);
#pragma unroll
        for (int j = 0; j < 2; ++j) {
          acc[i][j] = MFMA32(w0, xF[j][0], acc[i][j]);
          acc[i][j] = MFMA32(w1, xF[j][1], acc[i][j]);
        }
      }
    } else {
#pragma unroll
      for (int jf = 0; jf < 4; ++jf) {
        const short8 w0 = *(const short8*)(Wsh + (64 * wm + 16 * jf + lx) * 72 + q * 8);
        const short8 w1 = *(const short8*)(Wsh + (64 * wm + 16 * jf + lx) * 72 + 32 + q * 8);
#pragma unroll
        for (int i = 0; i < 2; ++i) {
          acc[jf][i] = MFMA32(xF[i][0], w0, acc[jf][i]);
          acc[jf][i] = MFMA32(xF[i][1], w1, acc[jf][i]);
        }
      }
    }
  }

  const int h = (f0 >> 6) + wm;
  if (which < 2) {
    unsigned short* Y = (which == 0 ? Kb : Qb);
    const float sc = (which == 0) ? SCALE_LOG2_ : 1.0f;
#pragma unroll
    for (int i = 0; i < 4; ++i)
#pragma unroll
      for (int j = 0; j < 2; ++j) {
        const int n = n0 + 32 * wn + 16 * j + lx;
        const int d0 = 16 * i + 4 * q;
        ushort4 u;
        u.x = f2bf(acc[i][j][0] * sc); u.y = f2bf(acc[i][j][1] * sc);
        u.z = f2bf(acc[i][j][2] * sc); u.w = f2bf(acc[i][j][3] * sc);
        *(ushort4*)(Y + ((size_t)((b * NH_ + h) * NTOK_ + n)) * DH_ + d0) = u;
      }
  } else {
#pragma unroll
    for (int jf = 0; jf < 4; ++jf)
#pragma unroll
      for (int i = 0; i < 2; ++i) {
        const int d = 16 * jf + lx;
        const int n = n0 + 32 * wn + 16 * i + 4 * q;
        ushort4 u;
        u.x = f2bf(acc[jf][i][0]); u.y = f2bf(acc[jf][i][1]);
        u.z = f2bf(acc[jf][i][2]); u.w = f2bf(acc[jf][i][3]);
        *(ushort4*)(Vt + ((size_t)((b * NH_ + h) * DH_ + d)) * NTOK_ + n) = u;
      }
  }
}

// ---------------------------------------------------------------------------
// Kernel 2: block-causal attention — waves partition j (not i): wave w owns
// j-quarter 32w..32w+31 for ALL 64 i. K B-frags for all 4 i-strips hoisted to
// registers; per iteration a wave reads only its own 4 KB of Q + 4 KB of V
// from LDS (4x less traffic than the i-partition). S^T register trick per
// (jc,ic). Partial O per wave (its j-quarter) -> one cross-wave LDS reduction
// at block end (pad stride 68). DMA double-buffer + swizzle as before.
// ---------------------------------------------------------------------------
__global__ __launch_bounds__(256, 2) void attn_kernel(
    const unsigned short* __restrict__ Kb, const unsigned short* __restrict__ Qb,
    const unsigned short* __restrict__ Vt, unsigned short* __restrict__ Ob) {
  // smem map: [0,16K)=Q0 [16K,32K)=Q1 [32K,48K)=V0 [48K,64K)=V1
  // epilogue reuse: [0,69632)=4x O-partial regions (64x68 fp32), [69632,+1K)=Lsum
  __shared__ __align__(16) char smem[70656];

  const int tid = threadIdx.x;
  const int lane = tid & 63;
  const int w = tid >> 6;      // j-quarter owner
  const int lx = lane & 15;
  const int g = lane >> 4;

  const int bid = blockIdx.x;      // 0..511
  const int u = bid >> 4;
  const int iblk = (u < 16) ? (31 - u) : (u - 16);   // LPT pairing
  const int bh = bid & 15;
  const int h = bh & 7, b = bh >> 3;
  const int i0 = iblk * 64;
  const int njt = (iblk >> 1) + 1;   // 128-wide j-tiles; 1..16

  const size_t bhs = (size_t)b * NH_ + h;
  const unsigned short* Kg = Kb + bhs * (size_t)NTOK_ * DH_ + (size_t)i0 * DH_;
  const unsigned short* Qg = Qb + bhs * (size_t)NTOK_ * DH_;
  const unsigned short* Vg = Vt + bhs * (size_t)DH_ * NTOK_;

  auto stage = [&](int buf, int j0) {
#pragma unroll
    for (int cc = 0; cc < 4; ++cc) {
      const int chunk = 4 * w + cc;
      {  // Q: chunk = 8 rows x 64 d
        const int row = chunk * 8 + (lane >> 3);
        const int grp = (lane & 7) ^ (row & 7);
        dma16(Qg + (size_t)(j0 + row) * DH_ + grp * 8,
              (unsigned short*)(smem + buf * 16384) + chunk * 512);
      }
      {  // V: chunk = 4 rows x 128 j
        const int row = chunk * 4 + (lane >> 4);
        const int grp = (lane & 15) ^ (row & 7);
        dma16(Vg + (size_t)row * NTOK_ + j0 + grp * 8,
              (unsigned short*)(smem + 32768 + buf * 16384) + chunk * 512);
      }
    }
  };

  // K B-frags for all 4 i-strips (one-time global reads, stay in registers)
  short8 aK[4][2];
#pragma unroll
  for (int ic = 0; ic < 4; ++ic) {
    aK[ic][0] = *(const short8*)(Kg + (16 * ic + lx) * DH_ + g * 8);
    aK[ic][1] = *(const short8*)(Kg + (16 * ic + lx) * DH_ + 32 + g * 8);
  }

  f32x4 o[4][4];   // o[t][ic]: O^T rows d=16t+4g+r, col i=16ic+lx (j-quarter partial)
#pragma unroll
  for (int t = 0; t < 4; ++t)
#pragma unroll
    for (int ic = 0; ic < 4; ++ic) o[t][ic] = (f32x4){0.f, 0.f, 0.f, 0.f};
  float rs[4] = {0.f, 0.f, 0.f, 0.f};

  const int fr0 = ((g ^ (lx & 7)) << 3);        // Q d-chunk g (swizzled)
  const int fr1 = (((4 + g) ^ (lx & 7)) << 3);  // Q d-chunk 4+g

  stage(0, 0);
  __syncthreads();   // drains DMA

  int cur = 0;
  for (int jt = 0; jt < njt; ++jt) {
    if (jt + 1 < njt) stage(cur ^ 1, (jt + 1) * 128);  // DMA overlaps compute

    const unsigned short* Qs = (const unsigned short*)(smem + cur * 16384);
    const unsigned short* Vs = (const unsigned short*)(smem + 32768 + cur * 16384);

#pragma unroll
    for (int jc = 0; jc < 2; ++jc) {
      // S^T: sa[ic] = S^T[j=32w+16jc+4g+r][i=16ic+lx]
      const int jrow = 32 * w + 16 * jc + lx;
      const short8 a0 = *(const short8*)(Qs + jrow * 64 + fr0);
      const short8 a1 = *(const short8*)(Qs + jrow * 64 + fr1);
      f32x4 sa[4];
#pragma unroll
      for (int ic = 0; ic < 4; ++ic) {
        sa[ic] = (f32x4){0.f, 0.f, 0.f, 0.f};
        sa[ic] = MFMA32(a0, aK[ic][0], sa[ic]);
        sa[ic] = MFMA32(a1, aK[ic][1], sa[ic]);
      }
      // exp2 -> own-register packed P (B operand of 16x16x16 over k=j)
      bfx4 pk[4];
#pragma unroll
      for (int ic = 0; ic < 4; ++ic) {
        const float p0 = __builtin_amdgcn_exp2f(sa[ic][0]);
        const float p1 = __builtin_amdgcn_exp2f(sa[ic][1]);
        const float p2 = __builtin_amdgcn_exp2f(sa[ic][2]);
        const float p3 = __builtin_amdgcn_exp2f(sa[ic][3]);
        rs[ic] += (p0 + p1) + (p2 + p3);
        union { unsigned u[2]; bfx4 v; } pkk;
        pkk.u[0] = (__builtin_bit_cast(unsigned, p0) >> 16) |
                   (__builtin_bit_cast(unsigned, p1) & 0xFFFF0000u);
        pkk.u[1] = (__builtin_bit_cast(unsigned, p2) >> 16) |
                   (__builtin_bit_cast(unsigned, p3) & 0xFFFF0000u);
        pk[ic] = pkk.v;
      }
      // PV: o[t][ic] += V^T A-frag (k=j chunk) x packed P
      const int jgrp = 4 * w + 2 * jc + (g >> 1);
      const int joff = (g & 1) << 2;
#pragma unroll
      for (int t = 0; t < 4; ++t) {
        const int vrow = 16 * t + lx;
        const bfx4 va = *(const bfx4*)(Vs + vrow * 128 +
                                       ((jgrp ^ (vrow & 7)) << 3) + joff);
#pragma unroll
        for (int ic = 0; ic < 4; ++ic) o[t][ic] = MFMA16(va, pk[ic], o[t][ic]);
      }
    }

    __syncthreads();   // drains next-tile DMA; guards double-buffer reuse
    cur ^= 1;
  }

  // ---- cross-wave reduction (buffers dead after final barrier) ----
  float* Ored = (float*)smem;               // region w: [i(64)][d(64)] stride 68
  float* Lsum = (float*)(smem + 69632);     // [w][i]
#pragma unroll
  for (int t = 0; t < 4; ++t)
#pragma unroll
    for (int ic = 0; ic < 4; ++ic)
      *(f32x4*)(Ored + w * 4352 + (16 * ic + lx) * 68 + 16 * t + 4 * g) = o[t][ic];
#pragma unroll
  for (int ic = 0; ic < 4; ++ic) {
    rs[ic] += __shfl_xor(rs[ic], 16);
    rs[ic] += __shfl_xor(rs[ic], 32);
  }
  if (lane < 16) {
#pragma unroll
    for (int ic = 0; ic < 4; ++ic) Lsum[w * 64 + 16 * ic + lx] = rs[ic];
  }
  __syncthreads();

  const int i = tid >> 2;
  const int dq = (tid & 3) * 16;
  const float l = Lsum[i] + Lsum[64 + i] + Lsum[128 + i] + Lsum[192 + i];
  const float invl = 1.0f / l;
  union { unsigned short us[16]; uint4 q[2]; } ob;
#pragma unroll
  for (int k = 0; k < 4; ++k) {
    const f32x4 v0 = *(const f32x4*)(Ored + 0 * 4352 + i * 68 + dq + 4 * k);
    const f32x4 v1 = *(const f32x4*)(Ored + 1 * 4352 + i * 68 + dq + 4 * k);
    const f32x4 v2 = *(const f32x4*)(Ored + 2 * 4352 + i * 68 + dq + 4 * k);
    const f32x4 v3 = *(const f32x4*)(Ored + 3 * 4352 + i * 68 + dq + 4 * k);
    const f32x4 s4 = (v0 + v1) + (v2 + v3);
    ob.us[4 * k + 0] = f2bf(s4[0] * invl);
    ob.us[4 * k + 1] = f2bf(s4[1] * invl);
    ob.us[4 * k + 2] = f2bf(s4[2] * invl);
    ob.us[4 * k + 3] = f2bf(s4[3] * invl);
  }
  const int n = i0 + i;
  unsigned short* dst = Ob + ((size_t)(b * NTOK_ + n)) * FF_ + h * 64 + dq;
  *(uint4*)(dst) = ob.q[0];
  *(uint4*)(dst + 8) = ob.q[1];
}

// ---------------------------------------------------------------------------
// Kernel 3: output projection via MFMA + bias + ReLU + skip -> d_out fp32.
// ---------------------------------------------------------------------------
__global__ __launch_bounds__(256) void proj_kernel(
    const unsigned short* __restrict__ Ob, const unsigned short* __restrict__ Wob,
    const float* __restrict__ bo, const float* __restrict__ x,
    float* __restrict__ pre) {
  __shared__ unsigned short Osh[64 * 72];
  __shared__ unsigned short Wsh[64 * 72];
  const int tid = threadIdx.x;
  const int lane = tid & 63, w = tid >> 6;
  const int lx = lane & 15, q = lane >> 4;
  const int wn = w & 1, wo = w >> 1;
  const int n0 = blockIdx.x * 64;
  const int o0 = blockIdx.y * 64;
  const int b = blockIdx.z;

  const int srow = tid >> 3;
  const int soff = (tid & 7) * 8;
  const unsigned short* Og = Ob + ((size_t)(b * NTOK_ + n0 + srow)) * FF_ + soff;
  const unsigned short* Wg = Wob + (size_t)(o0 + srow) * FF_ + soff;

  uint4 orr[2], wrr[2];
#pragma unroll
  for (int r = 0; r < 2; ++r) {
    orr[r] = *(const uint4*)(Og + (size_t)(32 * r) * FF_);
    wrr[r] = *(const uint4*)(Wg + (size_t)(32 * r) * FF_);
  }

  f32x4 acc[2][2];
#pragma unroll
  for (int i = 0; i < 2; ++i)
#pragma unroll
    for (int j = 0; j < 2; ++j) acc[i][j] = (f32x4){0.f, 0.f, 0.f, 0.f};

  for (int kk = 0; kk < 8; ++kk) {
    __syncthreads();
#pragma unroll
    for (int r = 0; r < 2; ++r) {
      *(uint4*)(Osh + (srow + 32 * r) * 72 + soff) = orr[r];
      *(uint4*)(Wsh + (srow + 32 * r) * 72 + soff) = wrr[r];
    }
    if (kk < 7) {
      const int c0 = (kk + 1) * 64;
#pragma unroll
      for (int r = 0; r < 2; ++r) {
        orr[r] = *(const uint4*)(Og + (size_t)(32 * r) * FF_ + c0);
        wrr[r] = *(const uint4*)(Wg + (size_t)(32 * r) * FF_ + c0);
      }
    }
    __syncthreads();
    short8 aF[2][2], bF[2][2];
#pragma unroll
    for (int i = 0; i < 2; ++i) {
      aF[i][0] = *(const short8*)(Osh + (32 * wn + 16 * i + lx) * 72 + q * 8);
      aF[i][1] = *(const short8*)(Osh + (32 * wn + 16 * i + lx) * 72 + 32 + q * 8);
      bF[i][0] = *(const short8*)(Wsh + (32 * wo + 16 * i + lx) * 72 + q * 8);
      bF[i][1] = *(const short8*)(Wsh + (32 * wo + 16 * i + lx) * 72 + 32 + q * 8);
    }
#pragma unroll
    for (int i = 0; i < 2; ++i)
#pragma unroll
      for (int j = 0; j < 2; ++j) {
        acc[i][j] = MFMA32(aF[i][0], bF[j][0], acc[i][j]);
        acc[i][j] = MFMA32(aF[i][1], bF[j][1], acc[i][j]);
      }
  }

#pragma unroll
  for (int j = 0; j < 2; ++j) {
    const int o = o0 + 32 * wo + 16 * j + lx;
    const float bias = bo[o];
#pragma unroll
    for (int i = 0; i < 2; ++i) {
      const int n = n0 + 32 * wn + 16 * i + 4 * q;
      const float4 xv = *(const float4*)(x + ((size_t)(b * CIN_ + o)) * NTOK_ + n);
      float4 v;
      v.x = fmaxf(acc[i][j][0] + bias, 0.f) + xv.x;
      v.y = fmaxf(acc[i][j][1] + bias, 0.f) + xv.y;
      v.z = fmaxf(acc[i][j][2] + bias, 0.f) + xv.z;
      v.w = fmaxf(acc[i][j][3] + bias, 0.f) + xv.w;
      *(float4*)(pre + ((size_t)(b * COUT_ + o)) * NTOK_ + n) = v;
    }
  }
}

// ---------------------------------------------------------------------------
// Kernel 4: BatchNorm, self-contained: one block per channel computes batch
// stats (in-register data) then normalizes in place.
// ---------------------------------------------------------------------------
__global__ __launch_bounds__(256) void bn_kernel(
    float* __restrict__ out, const float* __restrict__ gamma,
    const float* __restrict__ beta) {
  __shared__ float red[8];
  const int c = blockIdx.x;
  const int tid = threadIdx.x;
  const int lane = tid & 63, w = tid >> 6;

  float4 v[2][2];
  float s = 0.f, s2 = 0.f;
#pragma unroll
  for (int b = 0; b < BB_; ++b) {
    float* base = out + ((size_t)(b * COUT_ + c)) * NTOK_;
#pragma unroll
    for (int p = 0; p < 2; ++p) {
      const float4 t = *(const float4*)(base + 4 * tid + p * 1024);
      v[b][p] = t;
      s += t.x + t.y + t.z + t.w;
      s2 += t.x * t.x + t.y * t.y + t.z * t.z + t.w * t.w;
    }
  }
#pragma unroll
  for (int off = 32; off >= 1; off >>= 1) {
    s += __shfl_xor(s, off);
    s2 += __shfl_xor(s2, off);
  }
  if (lane == 0) { red[w] = s; red[4 + w] = s2; }
  __syncthreads();
  const float S = red[0] + red[1] + red[2] + red[3];
  const float S2 = red[4] + red[5] + red[6] + red[7];
  const float inv = 1.0f / (float)(BB_ * NTOK_);
  const float mean = S * inv;
  const float var = S2 * inv - mean * mean;
  const float sc = rsqrtf(var + BNEPS_) * gamma[c];
  const float bt = beta[c];
#pragma unroll
  for (int b = 0; b < BB_; ++b) {
    float* base = out + ((size_t)(b * COUT_ + c)) * NTOK_;
#pragma unroll
    for (int p = 0; p < 2; ++p) {
      float4 t = v[b][p];
      t.x = (t.x - mean) * sc + bt;
      t.y = (t.y - mean) * sc + bt;
      t.z = (t.z - mean) * sc + bt;
      t.w = (t.w - mean) * sc + bt;
      *(float4*)(base + 4 * tid + p * 1024) = t;
    }
  }
}

extern "C" void kernel_launch(void* const* d_in, const int* in_sizes, int n_in,
                              void* d_out, int out_size, void* d_ws, size_t ws_size,
                              hipStream_t stream) {
  (void)in_sizes; (void)n_in; (void)out_size; (void)ws_size;
  const float* x = (const float*)d_in[0];
  const float* WK = (const float*)d_in[1];
  const float* WQ = (const float*)d_in[2];
  const float* WV = (const float*)d_in[3];
  const float* Wo = (const float*)d_in[4];
  const float* bo = (const float*)d_in[5];
  const float* gamma = (const float*)d_in[6];
  const float* beta = (const float*)d_in[7];

  char* ws = (char*)d_ws;
  unsigned short* xT  = (unsigned short*)(ws);                    // 2 MB
  unsigned short* Wkb = (unsigned short*)(ws + 2097152);          // 256 KB x4
  unsigned short* Wqb = (unsigned short*)(ws + 2359296);
  unsigned short* Wvb = (unsigned short*)(ws + 2621440);
  unsigned short* Wob = (unsigned short*)(ws + 2883584);
  unsigned short* Kb  = (unsigned short*)(ws + 3145728);          // 4 MB
  unsigned short* Qb  = (unsigned short*)(ws + 7340032);          // 4 MB
  unsigned short* Vt  = (unsigned short*)(ws + 11534336);         // 4 MB
  unsigned short* Ob  = (unsigned short*)(ws + 15728640);         // 4 MB
  float* out = (float*)d_out;

  prep_kernel<<<384, 256, 0, stream>>>(x, WK, WQ, WV, Wo, xT, Wkb, Wqb, Wvb, Wob);
  qkv_kernel<<<dim3(32, 4, 6), 256, 0, stream>>>(xT, Wkb, Wqb, Wvb, Kb, Qb, Vt);
  attn_kernel<<<dim3(512, 1, 1), 256, 0, stream>>>(Kb, Qb, Vt, Ob);
  proj_kernel<<<dim3(32, 4, 2), 256, 0, stream>>>(Ob, Wob, bo, x, out);
  bn_kernel<<<256, 256, 0, stream>>>(out, gamma, beta);
}